// Round 3
// baseline (1399.881 us; speedup 1.0000x reference)
//
#include <hip/hip_runtime.h>
#include <math.h>

typedef unsigned long long u64;
typedef unsigned int u32;

// Problem constants
#define L 512
#define E 300
#define H 512          // per-direction hidden
#define G4H 2048       // 4*H
#define NTAGS 20
#define START_TAG 18
#define STOP_TAG 19

#define KC 100         // k1 K-chunk (300 = 3*100)

// Workspace layout (bytes) -- footprint UNCHANGED from the verified baseline
// (ends at 10543104; round-2 overflowed past it -> crash).
#define OFF_XW    0u          // f32 [2][512][2048] (permuted cols) = 8388608
#define OFF_HIST  8388608u    // f32 [2][512][512]  = 2097152
#define OFF_HBUF  10485760u   // u64 [2][2][512] canonical h slots = 16384
#define OFF_FEATS 10502144u   // f32 [512][20] = 40960. DEAD until k3 ->
                              // reused during k2 as:
                              //   +0     : mirror u64 [2][2][512] = 16384 B
                              //   +16384 : cntX  int[8]  (per-XCD tickets)
                              //   +16416 : claimed int[64] (slot bitmap)

// ---------------------------------------------------------------------------
// K0: zero mirror + control block (must run before every k2 replay; k3
// overwrites this region with feats afterwards, so tags would be garbage).
__global__ void k0_init(u64* __restrict__ z) {
    int t = threadIdx.x;
#pragma unroll
    for (int i = 0; i < 9; ++i) {
        int idx = t * 9 + i;            // 256*9 = 2304 u64 = 18432 B
        if (idx < 2304) z[idx] = 0;
    }
}

// ---------------------------------------------------------------------------
// K1: tiled GEMM  xw[dir][t][pos(n)] = embed[sent[t]] . wih[n] + bias(n).
// (unchanged from verified baseline)
__global__ __launch_bounds__(256) void k1_xw(
    const int* __restrict__ sentence, const float* __restrict__ embed,
    const float* __restrict__ wih_f, const float* __restrict__ wih_b,
    const float* __restrict__ bih_f, const float* __restrict__ bhh_f,
    const float* __restrict__ bih_b, const float* __restrict__ bhh_b,
    float* __restrict__ xw) {
    __shared__ float wST[KC][68];   // [k][n]
    __shared__ float xST[KC][68];   // [k][t]
    __shared__ int   sT[64];

    const int tid = threadIdx.x;
    const int tx = tid & 15;        // t micro index
    const int ty = tid >> 4;        // n micro index
    const int n_base = blockIdx.x * 64;
    const int t_base = blockIdx.y * 64;
    const int dir = blockIdx.z;
    const float* wih = dir ? wih_b : wih_f;
    const float* bih = dir ? bih_b : bih_f;
    const float* bhh = dir ? bhh_b : bhh_f;

    if (tid < 64) sT[tid] = sentence[t_base + tid];
    __syncthreads();

    float acc[4][4];
#pragma unroll
    for (int i = 0; i < 4; ++i)
#pragma unroll
        for (int j = 0; j < 4; ++j) acc[i][j] = 0.f;

    for (int kc = 0; kc < E; kc += KC) {
#pragma unroll
        for (int i = 0; i < 25; ++i) {
            int idx = i * 256 + tid;          // < 6400
            int row = idx / KC, col = idx % KC;
            wST[col][row] = wih[(size_t)(n_base + row) * E + kc + col];
        }
#pragma unroll
        for (int i = 0; i < 25; ++i) {
            int idx = i * 256 + tid;
            int trow = idx / KC, col = idx % KC;
            xST[col][trow] = embed[(size_t)sT[trow] * E + kc + col];
        }
        __syncthreads();

#pragma unroll 4
        for (int k = 0; k < KC; ++k) {
            float4 wv4 = *(const float4*)&wST[k][ty * 4];
            float4 xv4 = *(const float4*)&xST[k][tx * 4];
            float wv[4] = {wv4.x, wv4.y, wv4.z, wv4.w};
            float xv[4] = {xv4.x, xv4.y, xv4.z, xv4.w};
#pragma unroll
            for (int i = 0; i < 4; ++i)
#pragma unroll
                for (int j = 0; j < 4; ++j)
                    acc[i][j] = fmaf(wv[i], xv[j], acc[i][j]);
        }
        __syncthreads();
    }

#pragma unroll
    for (int i = 0; i < 4; ++i) {
        int n = n_base + ty * 4 + i;
        float b = bih[n] + bhh[n];
        int u = n & (H - 1), g = n >> 9;
        int pos = (u >> 4) * 64 + g * 16 + (u & 15);   // gate-major in block
#pragma unroll
        for (int j = 0; j < 4; ++j) {
            int t = t_base + tx * 4 + j;
            xw[((size_t)(dir * L) + t) * G4H + pos] = acc[i][j] + b;
        }
    }
}

// ---------------------------------------------------------------------------
// K2: bidirectional LSTM recurrence, XCD-clustered with deadlock-free
// fallback.
//
// Placement: 86.4KB LDS -> exactly 1 WG/CU; grid=256=CU count -> the
// dispatcher fills all 8 XCDs, 32 WGs each (common case). Per-XCD ticket:
// XCD0 ranks 0..31 CAS-claim fwd slots, XCD1 bwd slots. Every other WG is
// a SPARE: sleeps ~30us, then CAS-adopts any unclaimed slot (covers
// dispatch pathologies). Duplicate workers are idempotent (deterministic
// fp -> bitwise-identical publishes), so all races are safe; every slot is
// always covered -> no deadlock, regardless of placement.
//
// h-exchange, dual path:
//  - canonical: agent-scope atomic store/load (round-0-proven, correct
//    under ANY placement; ~MALL RT).
//  - mirror: plain sc0 store (write-through to the producer's L2) + sc0
//    load poll (L1 bypass, L2 hit). Coherent iff producer/consumer share
//    an XCD -- which the placement makes the common case. ~2-3x lower RT.
//  Consumers poll mirror 2-deep pipelined, with one canonical check per 2
//  mirror tries as the correctness backstop.
// Tag protocol (value|step in one 8B) unchanged -> replay-safe.
#define SHM_U64 10800   // 86400 B LDS: 2 WGs/CU impossible (172800 > 160K)

__global__ __launch_bounds__(512, 1) void k2_lstm(
    const float* __restrict__ whh_f, const float* __restrict__ whh_b,
    const float* __restrict__ h0, const float* __restrict__ c0,
    const float* __restrict__ xw, float* __restrict__ hist,
    u64* __restrict__ hbuf, u64* __restrict__ mir,
    int* __restrict__ cntX, int* __restrict__ claimed) {

    __shared__ u64 shm[SHM_U64];
    float* pbuf = (float*)(shm + 8);           // [2][8][68] floats = 4352 B
#define PB(p, w, l) pbuf[(((p) * 8 + (w)) * 68) + (l)]
    __shared__ int slot_sh;

    const int tid = threadIdx.x;

    // --- slot assignment: primary claim, spare adoption ---
    if (tid == 0) {
        shm[SHM_U64 - 1] = 0;                  // keep LDS tail alive
        u32 xcd = __builtin_amdgcn_s_getreg(14356) & 7;  // hwreg(20,0,8)
        int r = atomicAdd(&cntX[xcd], 1);      // device-scope ticket
        int slot = -1;
        if (xcd <= 1 && r < 32) {
            int cand = (int)xcd * 32 + r;      // XCD0->fwd 0..31, XCD1->bwd
            if (atomicCAS(&claimed[cand], 0, 1) == 0) slot = cand;
        }
        slot_sh = slot;
    }
    __syncthreads();
    int slot = slot_sh;

    if (slot < 0) {
        // spare: give primaries ~30us to register, then adopt stragglers
        if (tid == 0) {
            for (int i = 0; i < 8; ++i) __builtin_amdgcn_s_sleep(127);
            int got = -1;
            for (int sl = 0; sl < 64 && got < 0; ++sl)
                if (atomicCAS(&claimed[sl], 0, 1) == 0) got = sl;
            slot_sh = got;
        }
        __syncthreads();
        slot = slot_sh;
        if (slot < 0) return;                  // all slots covered -> exit
    }

    const int dir = slot >> 5;
    const int wg  = slot & 31;
    const int wv  = tid >> 6;       // wave id = dot k-slice
    const int l   = tid & 63;
    const int g   = l >> 4;         // gate: 0=i 1=f 2=g 3=o
    const int j   = l & 15;         // unit within WG
    const int grow = g * H + wg * 16 + j;

    const float* whh = dir ? whh_b : whh_f;
    float* histd = hist + (size_t)dir * L * H;
    u64* hb   = hbuf + dir * 1024;  // canonical [parity][512]
    u64* mird = mir  + dir * 1024;  // mirror    [parity][512]

    // this lane's 64 Whh weights (row grow, slice wv) -> regs
    float w[64];
    {
        const float* wp = whh + (size_t)grow * H + wv * 64;
#pragma unroll
        for (int i = 0; i < 64; i += 4) {
            float4 v = *(const float4*)(wp + i);
            w[i] = v.x; w[i+1] = v.y; w[i+2] = v.z; w[i+3] = v.w;
        }
    }

    // c state lives on wave0 lanes 0..15 (unit = wg*16 + tid)
    float c = (tid < 16) ? c0[dir * H + wg * 16 + tid] : 0.f;

    for (int s = 1; s <= L; ++s) {
        const int t = dir ? (L - s) : (s - 1);
        const int par = s & 1;

        // ---- acquire h_{s-1}[tid]: mirror fast path + canonical backstop --
        float hval;
        if (s == 1) {
            hval = h0[dir * H + tid];
        } else {
            const u32 want = (u32)(s - 1);
            const u64* mslot = mird + ((s - 1) & 1) * 512 + tid;
            u64* cslot = hb + ((s - 1) & 1) * 512 + tid;
            u64 va, vb, got;
            // prime 2-deep mirror pipeline (early-clobber: loads must not
            // alias the address pair)
            asm volatile("global_load_dwordx2 %0, %2, off sc0\n\t"
                         "global_load_dwordx2 %1, %2, off sc0"
                         : "=&v"(va), "=&v"(vb)
                         : "v"(mslot) : "memory");
            while (true) {
                // oldest = va done when <=1 vmem outstanding (prior-step
                // stores were issued earlier, so this also drains them --
                // conservative but correct)
                asm volatile("s_waitcnt vmcnt(1)" : "+v"(va) :: "memory");
                __builtin_amdgcn_sched_barrier(0);
                if ((u32)(va >> 32) == want) { got = va; break; }
                asm volatile("global_load_dwordx2 %0, %1, off sc0"
                             : "=&v"(va) : "v"(mslot) : "memory");
                asm volatile("s_waitcnt vmcnt(1)" : "+v"(vb) :: "memory");
                __builtin_amdgcn_sched_barrier(0);
                if ((u32)(vb >> 32) == want) { got = vb; break; }
                asm volatile("global_load_dwordx2 %0, %1, off sc0"
                             : "=&v"(vb) : "v"(mslot) : "memory");
                // canonical backstop (agent scope; correct for any XCD)
                u64 vc = __hip_atomic_load(cslot, __ATOMIC_RELAXED,
                                           __HIP_MEMORY_SCOPE_AGENT);
                if ((u32)(vc >> 32) == want) { got = vc; break; }
            }
            hval = __uint_as_float((u32)got);
        }

        // xw prefetch AFTER the poll (keeps hand-counted vmcnt honest);
        // overlaps the dot below, consumed in the funnel.
        float xwv = 0.f;
        if (tid < 64)
            xwv = xw[((size_t)(dir * L) + t) * G4H + wg * 64 + l];

        // ---- dot: row l over slice wv via readlane broadcast, 4 accs ----
        float a0 = 0.f, a1 = 0.f, a2 = 0.f, a3 = 0.f;
#pragma unroll
        for (int i = 0; i < 64; i += 4) {
            float h0v = __uint_as_float((u32)__builtin_amdgcn_readlane(
                            (int)__float_as_uint(hval), i));
            float h1v = __uint_as_float((u32)__builtin_amdgcn_readlane(
                            (int)__float_as_uint(hval), i + 1));
            float h2v = __uint_as_float((u32)__builtin_amdgcn_readlane(
                            (int)__float_as_uint(hval), i + 2));
            float h3v = __uint_as_float((u32)__builtin_amdgcn_readlane(
                            (int)__float_as_uint(hval), i + 3));
            a0 = fmaf(w[i],     h0v, a0);
            a1 = fmaf(w[i + 1], h1v, a1);
            a2 = fmaf(w[i + 2], h2v, a2);
            a3 = fmaf(w[i + 3], h3v, a3);
        }
        PB(par, wv, l) = (a0 + a1) + (a2 + a3);
        __syncthreads();

        // ---- wave0 funnel tail: reduce 8 partials, gates, publish ----
        if (tid < 64) {
            float tot = 0.f;
#pragma unroll
            for (int p = 0; p < 8; ++p) tot += PB(par, p, l);
            float pre = tot + xwv;
            float aa = (g == 2) ? 2.f * pre : pre;       // tanh = 2*sig(2x)-1
            float sg = 1.f / (1.f + __expf(-aa));
            float vg = (g == 2) ? (2.f * sg - 1.f) : sg;
            float gi = __shfl(vg, j);
            float gf = __shfl(vg, 16 + j);
            float gg = __shfl(vg, 32 + j);
            float go = __shfl(vg, 48 + j);
            if (tid < 16) {
                c = gf * c + gi * gg;
                float th = 2.f / (1.f + __expf(-2.f * c)) - 1.f;
                float hout = go * th;
                u64 e = ((u64)(u32)s << 32) | (u64)__float_as_uint(hout);
                const u64* ma = mird + par * 512 + wg * 16 + tid;
                // mirror first: fast local-L2 visibility for co-XCD peers
                asm volatile("global_store_dwordx2 %0, %1, off sc0"
                             :: "v"(ma), "v"(e) : "memory");
                // canonical: device-scope, correct under any placement
                __hip_atomic_store(hb + par * 512 + wg * 16 + tid, e,
                                   __ATOMIC_RELAXED, __HIP_MEMORY_SCOPE_AGENT);
                histd[(size_t)t * H + wg * 16 + tid] = hout;
            }
        }
        // pbuf parity double-buffer + the single barrier covers reuse
    }
#undef PB
}

// ---------------------------------------------------------------------------
// K3: feats[t][tag] = b_out[tag] + concat(hf,hb)[t] . w_out[tag]   (f32)
__global__ void k3_feats(const float* __restrict__ hist,
                         const float* __restrict__ wout,
                         const float* __restrict__ bout,
                         float* __restrict__ feats) {
    int t = blockIdx.x;
    int tid = threadIdx.x;
    int tag = tid >> 4;       // [0,20)
    int part = tid & 15;
    const float* h0p = hist + (size_t)t * H;
    const float* h1p = hist + (size_t)L * H + (size_t)t * H;
    int j0 = part * 64;
    float acc = 0.f;
    for (int jj = 0; jj < 64; jj += 4) {
        int j = j0 + jj;
        float4 w4 = *(const float4*)(wout + (size_t)tag * (2 * H) + j);
        float4 h4 = (j < H) ? *(const float4*)(h0p + j)
                            : *(const float4*)(h1p + (j - H));
        acc = fmaf(w4.x, h4.x, fmaf(w4.y, h4.y,
              fmaf(w4.z, h4.z, fmaf(w4.w, h4.w, acc))));
    }
    acc += __shfl_xor(acc, 8, 16);
    acc += __shfl_xor(acc, 4, 16);
    acc += __shfl_xor(acc, 2, 16);
    acc += __shfl_xor(acc, 1, 16);
    if (part == 0) feats[(size_t)t * NTAGS + tag] = acc + bout[tag];
}

// ---------------------------------------------------------------------------
// K4: Viterbi + backtrack, one wave. Batched shfls + index-carrying tree-max
// (exact first-max semantics).
__global__ void k4_viterbi(const float* __restrict__ feats,
                           const float* __restrict__ trans,
                           int* __restrict__ out) {
    __shared__ unsigned char bp[L * NTAGS];
    int lane = threadIdx.x;           // 64 threads
    bool act = lane < NTAGS;

    float trl[NTAGS];
#pragma unroll
    for (int p = 0; p < NTAGS; ++p)
        trl[p] = act ? trans[lane * NTAGS + p] : -1.0e30f;

    float fv = (lane == START_TAG) ? 0.f : -10000.f;
    float nf = act ? feats[lane] : 0.f;

    for (int t = 0; t < L; ++t) {
        float f = nf;
        if (act && t + 1 < L) nf = feats[(size_t)(t + 1) * NTAGS + lane];
        float tv[NTAGS];
        int   ti[NTAGS];
#pragma unroll
        for (int p = 0; p < NTAGS; ++p) {
            tv[p] = __shfl(fv, p) + trl[p];
            ti[p] = p;
        }
#pragma unroll
        for (int p = 0; p < 4; ++p) {
            bool take = (tv[p + 16] > tv[p]) ||
                        (tv[p + 16] == tv[p] && ti[p + 16] < ti[p]);
            if (take) { tv[p] = tv[p + 16]; ti[p] = ti[p + 16]; }
        }
#pragma unroll
        for (int w = 8; w >= 1; w >>= 1)
#pragma unroll
            for (int p = 0; p < 16; ++p) if (p < w) {
                bool take = (tv[p + w] > tv[p]) ||
                            (tv[p + w] == tv[p] && ti[p + w] < ti[p]);
                if (take) { tv[p] = tv[p + w]; ti[p] = ti[p + w]; }
            }
        fv = tv[0] + f;
        if (act) bp[t * NTAGS + lane] = (unsigned char)ti[0];
    }

    float ts = act ? fv + trans[STOP_TAG * NTAGS + lane] : -1.0e30f;
    int bi = lane;
#pragma unroll
    for (int off = 32; off; off >>= 1) {
        float ov = __shfl_down(ts, off);
        int   oi = __shfl_down(bi, off);
        if (ov > ts) { ts = ov; bi = oi; }
    }
    if (lane == 0) {
        int tag = bi;
        out[L - 1] = tag;
        for (int t = L - 1; t >= 1; --t) {
            tag = bp[t * NTAGS + tag];
            out[t - 1] = tag;
        }
    }
}

// ---------------------------------------------------------------------------
extern "C" void kernel_launch(void* const* d_in, const int* in_sizes, int n_in,
                              void* d_out, int out_size, void* d_ws, size_t ws_size,
                              hipStream_t stream) {
    const int*   sentence = (const int*)d_in[0];
    const float* embed    = (const float*)d_in[1];
    const float* wih_f    = (const float*)d_in[2];
    const float* whh_f    = (const float*)d_in[3];
    const float* bih_f    = (const float*)d_in[4];
    const float* bhh_f    = (const float*)d_in[5];
    const float* wih_b    = (const float*)d_in[6];
    const float* whh_b    = (const float*)d_in[7];
    const float* bih_b    = (const float*)d_in[8];
    const float* bhh_b    = (const float*)d_in[9];
    const float* h0       = (const float*)d_in[10];
    const float* c0       = (const float*)d_in[11];
    const float* wout     = (const float*)d_in[12];
    const float* bout     = (const float*)d_in[13];
    const float* trans    = (const float*)d_in[14];
    int* out = (int*)d_out;

    char* ws = (char*)d_ws;
    float* xw    = (float*)(ws + OFF_XW);
    float* hist  = (float*)(ws + OFF_HIST);
    float* feats = (float*)(ws + OFF_FEATS);
    u64*   hbuf  = (u64*)(ws + OFF_HBUF);
    u64*   mir   = (u64*)(ws + OFF_FEATS);            // dead until k3
    int*   cntX  = (int*)(ws + OFF_FEATS + 16384);
    int*   claimed = cntX + 8;

    k0_init<<<1, 256, 0, stream>>>(mir);
    k1_xw<<<dim3(32, 8, 2), 256, 0, stream>>>(sentence, embed, wih_f, wih_b,
                                              bih_f, bhh_f, bih_b, bhh_b, xw);
    k2_lstm<<<256, 512, 0, stream>>>(whh_f, whh_b, h0, c0, xw, hist, hbuf,
                                     mir, cntX, claimed);
    k3_feats<<<L, 320, 0, stream>>>(hist, wout, bout, feats);
    k4_viterbi<<<1, 64, 0, stream>>>(feats, trans, out);
}